// Round 8
// baseline (225.513 us; speedup 1.0000x reference)
//
#include <hip/hip_runtime.h>
#include <hip/hip_bf16.h>

#define THREADS 256
#define GTHREADS 512   // gemm block size (8 waves)

typedef _Float16 half4_t __attribute__((ext_vector_type(4)));
typedef _Float16 half8_t __attribute__((ext_vector_type(8)));

__device__ inline float4 load4(const float* p) {
    return *reinterpret_cast<const float4*>(p);
}
__device__ inline float4 load4(const _Float16* p) {
    const half4_t t = *reinterpret_cast<const half4_t*>(p);
    return make_float4((float)t.x, (float)t.y, (float)t.z, (float)t.w);
}
__device__ inline void store4h(_Float16* p, float4 v) {
    half4_t t;
    t.x = (_Float16)v.x; t.y = (_Float16)v.y;
    t.z = (_Float16)v.z; t.w = (_Float16)v.w;
    *reinterpret_cast<half4_t*>(p) = t;
}

// ---------------------------------------------------------------------------
// Fused dual-GEMM + (optional) CSR placement.
//   blocks [0, place_blocks)          : csr[atomicAdd(cursor[dst[e]])] = src[e]
//   blocks [place_blocks, ...)        : outl = in @ Wl, outr = in @ Wr
// The two phases have no data dependency; place is memory-latency-bound,
// gemm is VALU-bound -> co-residency overlaps them in one dispatch.
// GEMM: c4 = lane&15 -> col group, rg = lane>>4 -> row-in-group (per-lane
// row addresses defeat auto-scalarization => global vector loads, vmcnt
// pipelining). W staged in LDS in K-tiles of 64 (32 KB total) via straight
// coalesced float4 copy; ds_read_b128 at 2-way bank aliasing = free.
// No early return: rows clamped, stores guarded (in-loop barriers uniform).
// ---------------------------------------------------------------------------
template<typename Tin, int K, int R>
__global__ __launch_bounds__(GTHREADS, 4) void gemm_place(
    const Tin* __restrict__ in, const float* __restrict__ Wl,
    const float* __restrict__ Wr, _Float16* __restrict__ outl,
    _Float16* __restrict__ outr, int nrows,
    const int* __restrict__ src, const int* __restrict__ dst,
    int* __restrict__ cursor, int* __restrict__ csr, int nedges,
    int place_blocks)
{
    if (blockIdx.x < (unsigned)place_blocks) {
        const int e = blockIdx.x * GTHREADS + threadIdx.x;
        if (e < nedges) {
            const int pos = atomicAdd(&cursor[dst[e]], 1);
            csr[pos] = src[e];
        }
        return;
    }

    constexpr int KT = 64;                      // k-tile (LDS = 32 KB)
    __shared__ float4 sWl[KT * 16];             // [k][c4] : W[k][4c4..4c4+3]
    __shared__ float4 sWr[KT * 16];

    const int lane = threadIdx.x & 63;
    const int wid  = threadIdx.x >> 6;          // 0..7
    const int c4   = lane & 15;                 // col group
    const int rg   = lane >> 4;                 // 0..3 row-in-group
    const int gbid = blockIdx.x - place_blocks;
    const int wrow0 = gbid * (8 * 4 * R) + wid * (4 * R);

    int rr[R];
    #pragma unroll
    for (int r = 0; r < R; ++r) {
        const int row = wrow0 + r * 4 + rg;
        rr[r] = (row < nrows) ? row : (nrows - 1);   // clamp loads
    }

    float4 accl[R], accr[R];
    #pragma unroll
    for (int r = 0; r < R; ++r) {
        accl[r] = make_float4(0.f, 0.f, 0.f, 0.f);
        accr[r] = make_float4(0.f, 0.f, 0.f, 0.f);
    }

    for (int kt = 0; kt < K; kt += KT) {
        {   // stage W[kt .. kt+KT) for both matrices (coalesced float4 copy)
            const float4* gWl = reinterpret_cast<const float4*>(Wl + kt * 64);
            const float4* gWr = reinterpret_cast<const float4*>(Wr + kt * 64);
            for (int i = threadIdx.x; i < KT * 16; i += GTHREADS) {
                sWl[i] = gWl[i];
                sWr[i] = gWr[i];
            }
        }
        __syncthreads();

        #pragma unroll 2
        for (int k4 = 0; k4 < KT / 4; ++k4) {
            float4 xv[R];
            #pragma unroll
            for (int r = 0; r < R; ++r)
                xv[r] = load4(in + (size_t)rr[r] * K + kt + k4 * 4);

            float4 wl[4], wr[4];
            #pragma unroll
            for (int j = 0; j < 4; ++j) {
                wl[j] = sWl[(k4 * 4 + j) * 16 + c4];
                wr[j] = sWr[(k4 * 4 + j) * 16 + c4];
            }

            #pragma unroll
            for (int r = 0; r < R; ++r) {
                const float x0 = xv[r].x, x1 = xv[r].y, x2 = xv[r].z, x3 = xv[r].w;
                accl[r].x = fmaf(x0, wl[0].x, accl[r].x);
                accl[r].y = fmaf(x0, wl[0].y, accl[r].y);
                accl[r].z = fmaf(x0, wl[0].z, accl[r].z);
                accl[r].w = fmaf(x0, wl[0].w, accl[r].w);
                accl[r].x = fmaf(x1, wl[1].x, accl[r].x);
                accl[r].y = fmaf(x1, wl[1].y, accl[r].y);
                accl[r].z = fmaf(x1, wl[1].z, accl[r].z);
                accl[r].w = fmaf(x1, wl[1].w, accl[r].w);
                accl[r].x = fmaf(x2, wl[2].x, accl[r].x);
                accl[r].y = fmaf(x2, wl[2].y, accl[r].y);
                accl[r].z = fmaf(x2, wl[2].z, accl[r].z);
                accl[r].w = fmaf(x2, wl[2].w, accl[r].w);
                accl[r].x = fmaf(x3, wl[3].x, accl[r].x);
                accl[r].y = fmaf(x3, wl[3].y, accl[r].y);
                accl[r].z = fmaf(x3, wl[3].z, accl[r].z);
                accl[r].w = fmaf(x3, wl[3].w, accl[r].w);

                accr[r].x = fmaf(x0, wr[0].x, accr[r].x);
                accr[r].y = fmaf(x0, wr[0].y, accr[r].y);
                accr[r].z = fmaf(x0, wr[0].z, accr[r].z);
                accr[r].w = fmaf(x0, wr[0].w, accr[r].w);
                accr[r].x = fmaf(x1, wr[1].x, accr[r].x);
                accr[r].y = fmaf(x1, wr[1].y, accr[r].y);
                accr[r].z = fmaf(x1, wr[1].z, accr[r].z);
                accr[r].w = fmaf(x1, wr[1].w, accr[r].w);
                accr[r].x = fmaf(x2, wr[2].x, accr[r].x);
                accr[r].y = fmaf(x2, wr[2].y, accr[r].y);
                accr[r].z = fmaf(x2, wr[2].z, accr[r].z);
                accr[r].w = fmaf(x2, wr[2].w, accr[r].w);
                accr[r].x = fmaf(x3, wr[3].x, accr[r].x);
                accr[r].y = fmaf(x3, wr[3].y, accr[r].y);
                accr[r].z = fmaf(x3, wr[3].z, accr[r].z);
                accr[r].w = fmaf(x3, wr[3].w, accr[r].w);
            }
        }
        __syncthreads();
    }

    #pragma unroll
    for (int r = 0; r < R; ++r) {
        const int row = wrow0 + r * 4 + rg;
        if (row < nrows) {
            store4h(outl + (size_t)row * 64 + c4 * 4, accl[r]);
            store4h(outr + (size_t)row * 64 + c4 * 4, accr[r]);
        }
    }
}

// ---------------------------------------------------------------------------
// CSR build: histogram of dst, exclusive scan.
// ---------------------------------------------------------------------------
__global__ __launch_bounds__(THREADS) void hist_kernel(
    const int* __restrict__ dst, int* __restrict__ deg, int nedges)
{
    const int e = blockIdx.x * THREADS + threadIdx.x;
    if (e < nedges) atomicAdd(&deg[dst[e]], 1);
}

__global__ __launch_bounds__(THREADS) void scan_reduce(
    const int* __restrict__ deg, int* __restrict__ bsum, int n)
{
    __shared__ int s[THREADS];
    const int i = blockIdx.x * THREADS + threadIdx.x;
    s[threadIdx.x] = (i < n) ? deg[i] : 0;
    __syncthreads();
    for (int off = THREADS / 2; off > 0; off >>= 1) {
        if (threadIdx.x < off) s[threadIdx.x] += s[threadIdx.x + off];
        __syncthreads();
    }
    if (threadIdx.x == 0) bsum[blockIdx.x] = s[0];
}

// single block; nb <= THREADS
__global__ __launch_bounds__(THREADS) void scan_top(int* __restrict__ bsum, int nb)
{
    __shared__ int s[THREADS];
    const int t = threadIdx.x;
    const int v = (t < nb) ? bsum[t] : 0;
    s[t] = v;
    __syncthreads();
    for (int off = 1; off < THREADS; off <<= 1) {
        const int a = (t >= off) ? s[t - off] : 0;
        __syncthreads();
        s[t] += a;
        __syncthreads();
    }
    if (t < nb) bsum[t] = s[t] - v;   // exclusive
}

__global__ __launch_bounds__(THREADS) void scan_apply(
    const int* __restrict__ deg, const int* __restrict__ bsum,
    int* __restrict__ offs, int* __restrict__ cursor, int n)
{
    __shared__ int s[THREADS];
    const int t = threadIdx.x;
    const int i = blockIdx.x * THREADS + t;
    const int v = (i < n) ? deg[i] : 0;
    s[t] = v;
    __syncthreads();
    for (int off = 1; off < THREADS; off <<= 1) {
        const int a = (t >= off) ? s[t - off] : 0;
        __syncthreads();
        s[t] += a;
        __syncthreads();
    }
    if (i < n) {
        const int ex = bsum[blockIdx.x] + s[t] - v;
        offs[i] = ex;
        cursor[i] = ex;
    }
}

// ---------------------------------------------------------------------------
// Fused mean-aggregate + combine (fp16 payload, fp32 accumulation):
//   out[node,lane] = [relu]( (sum_{s in csr[node]} y[s,lane]) / max(deg,1)
//                            + bias[lane] + right[node,lane] )
// One wave per node, lane = channel (128B coalesced row reads).
// ---------------------------------------------------------------------------
__global__ __launch_bounds__(THREADS) void aggregate_fused(
    const _Float16* __restrict__ y, const int* __restrict__ csr,
    const int* __restrict__ offs, const int* __restrict__ deg,
    const _Float16* __restrict__ right, const float* __restrict__ bias,
    _Float16* __restrict__ out, int n, int relu)
{
    int node = blockIdx.x * (THREADS / 64) + (threadIdx.x >> 6);
    if (node >= n) return;
    node = __builtin_amdgcn_readfirstlane(node);   // wave-uniform
    const int lane = threadIdx.x & 63;
    const int start = __builtin_amdgcn_readfirstlane(offs[node]);
    const int d     = __builtin_amdgcn_readfirstlane(deg[node]);

    float acc = 0.f;
    int i = 0;
    for (; i + 4 <= d; i += 4) {
        const int s0 = __builtin_amdgcn_readfirstlane(csr[start + i + 0]);
        const int s1 = __builtin_amdgcn_readfirstlane(csr[start + i + 1]);
        const int s2 = __builtin_amdgcn_readfirstlane(csr[start + i + 2]);
        const int s3 = __builtin_amdgcn_readfirstlane(csr[start + i + 3]);
        const float a0 = (float)y[(size_t)s0 * 64 + lane];
        const float a1 = (float)y[(size_t)s1 * 64 + lane];
        const float a2 = (float)y[(size_t)s2 * 64 + lane];
        const float a3 = (float)y[(size_t)s3 * 64 + lane];
        acc += a0 + a1 + a2 + a3;
    }
    for (; i < d; ++i) {
        const int s = __builtin_amdgcn_readfirstlane(csr[start + i]);
        acc += (float)y[(size_t)s * 64 + lane];
    }

    const float inv = 1.0f / (float)(d > 0 ? d : 1);
    float v = fmaf(acc, inv, bias[lane] + (float)right[(size_t)node * 64 + lane]);
    if (relu) v = fmaxf(v, 0.f);
    out[(size_t)node * 64 + lane] = (_Float16)v;
}

// ---------------------------------------------------------------------------
// out[e] = dot(z[src[e]], z[dst[e]]) over 64 ch (fp16 z, fp32 accum);
// 8 lanes/edge, 16B loads, shfl reduce over 8.
// ---------------------------------------------------------------------------
__global__ __launch_bounds__(THREADS) void score_kernel(
    const _Float16* __restrict__ z, const int* __restrict__ src,
    const int* __restrict__ dst, float* __restrict__ out, int nedges)
{
    const int gid = blockIdx.x * THREADS + threadIdx.x;
    const int e = gid >> 3;
    const int g = gid & 7;
    if (e >= nedges) return;
    const int s = src[e];
    const int d = dst[e];
    const half8_t a = *reinterpret_cast<const half8_t*>(z + (size_t)s * 64 + g * 8);
    const half8_t b = *reinterpret_cast<const half8_t*>(z + (size_t)d * 64 + g * 8);
    float p = 0.f;
    #pragma unroll
    for (int j = 0; j < 8; ++j)
        p = fmaf((float)a[j], (float)b[j], p);
    p += __shfl_down(p, 4, 8);
    p += __shfl_down(p, 2, 8);
    p += __shfl_down(p, 1, 8);
    if (g == 0) out[e] = p;
}

extern "C" void kernel_launch(void* const* d_in, const int* in_sizes, int n_in,
                              void* d_out, int out_size, void* d_ws, size_t ws_size,
                              hipStream_t stream)
{
    const float* x   = (const float*)d_in[0];   // [N, 128]
    const int*   ei  = (const int*)  d_in[1];   // [2, E]
    const float* W1l = (const float*)d_in[2];   // [128, 64]
    const float* b1  = (const float*)d_in[3];   // [64]
    const float* W1r = (const float*)d_in[4];   // [128, 64]
    const float* W2l = (const float*)d_in[5];   // [64, 64]
    const float* b2  = (const float*)d_in[6];   // [64]
    const float* W2r = (const float*)d_in[7];   // [64, 64]
    float* out = (float*)d_out;

    const int N = in_sizes[0] / 128;            // 50000
    const int E = in_sizes[1] / 2;              // 800000
    const int* src = ei;
    const int* dst = ei + E;

    const size_t N64 = (size_t)N * 64;
    _Float16* tmp = (_Float16*)d_ws;            // [N,64]  in @ Wl (messages)
    _Float16* h   = tmp + N64;                  // [N,64]  layer-1 output
    _Float16* z   = h + N64;                    // [N,64]  layer-2 output
    int* deg    = (int*)(z + N64);              // [N]
    int* offs   = deg + N;                      // [N]
    int* cursor = offs + N;                     // [N]
    int* csr    = cursor + N;                   // [E]
    int* bsum   = csr + E;                      // [ceil(N/256)]

    constexpr int R = 4;                        // row-iters per lane
    const int rows_per_block = 8 * 4 * R;       // 8 waves x 4 rows x R = 128
    const int nb           = (N + THREADS - 1) / THREADS;      // scan blocks
    const int edge_blocks  = (E + THREADS - 1) / THREADS;
    const int gemm_blocks  = (N + rows_per_block - 1) / rows_per_block;
    const int place_blocks = (E + GTHREADS - 1) / GTHREADS;
    const int aggr_blocks  = (N + 3) / 4;                      // 4 nodes/block
    const int scor_blocks  = (E * 8 + THREADS - 1) / THREADS;

    // ---- CSR prefix (histogram + scan; shared by both layers) ----
    hipMemsetAsync(deg, 0, (size_t)N * sizeof(int), stream);
    hist_kernel<<<edge_blocks, THREADS, 0, stream>>>(dst, deg, E);
    scan_reduce<<<nb, THREADS, 0, stream>>>(deg, bsum, N);
    scan_top<<<1, THREADS, 0, stream>>>(bsum, nb);
    scan_apply<<<nb, THREADS, 0, stream>>>(deg, bsum, offs, cursor, N);

    // ---- layer 1 GEMM overlapped with CSR placement (independent work) ----
    gemm_place<float, 128, R><<<place_blocks + gemm_blocks, GTHREADS, 0, stream>>>(
        x, W1l, W1r, tmp, h, N, src, dst, cursor, csr, E, place_blocks);
    aggregate_fused<<<aggr_blocks, THREADS, 0, stream>>>(tmp, csr, offs, deg, h, b1, h, N, 1);

    // ---- layer 2 ----
    gemm_place<_Float16, 64, R><<<gemm_blocks, GTHREADS, 0, stream>>>(
        h, W2l, W2r, tmp, z, N, nullptr, nullptr, nullptr, nullptr, 0, 0);
    aggregate_fused<<<aggr_blocks, THREADS, 0, stream>>>(tmp, csr, offs, deg, z, b2, z, N, 0);

    // ---- decode ----
    score_kernel<<<scor_blocks, THREADS, 0, stream>>>(z, src, dst, out, E);
}

// Round 9
// 200.703 us; speedup vs baseline: 1.1236x; 1.1236x over previous
//
#include <hip/hip_runtime.h>
#include <hip/hip_bf16.h>

#define THREADS 256
#define GTHREADS 512   // gemm block size (8 waves)

typedef _Float16 half4_t __attribute__((ext_vector_type(4)));
typedef _Float16 half8_t __attribute__((ext_vector_type(8)));

__device__ inline float4 load4(const float* p) {
    return *reinterpret_cast<const float4*>(p);
}
__device__ inline float4 load4(const _Float16* p) {
    const half4_t t = *reinterpret_cast<const half4_t*>(p);
    return make_float4((float)t.x, (float)t.y, (float)t.z, (float)t.w);
}
__device__ inline void store4h(_Float16* p, float4 v) {
    half4_t t;
    t.x = (_Float16)v.x; t.y = (_Float16)v.y;
    t.z = (_Float16)v.z; t.w = (_Float16)v.w;
    *reinterpret_cast<half4_t*>(p) = t;
}

// ---------------------------------------------------------------------------
// Dual GEMM with CSR placement INTERLEAVED into every wave.
// Each block: (a) owns EPT edges/thread of the counting-sort placement
// (coalesced src/dst loads at start; independent atomicAdds fired after
// k-tile 0 so their latency hides under k-tile 1's FMAs; dependent csr
// stores retire at the end), and (b) computes 128 rows of outl = in @ Wl,
// outr = in @ Wr. GEMM lane map: c4 = lane&15 -> col group, rg = lane>>4 ->
// row-in-group (per-lane row addresses defeat auto-scalarization => global
// vector loads on the vmcnt path). W staged in LDS in K-tiles of 64 (32 KB)
// via straight coalesced float4 copy; ds_read_b128, 2-way aliasing = free.
// No early returns: rows clamped, stores guarded (barriers stay uniform).
// ---------------------------------------------------------------------------
template<typename Tin, int K, int R, int EPT>
__global__ __launch_bounds__(GTHREADS, 4) void gemm_place(
    const Tin* __restrict__ in, const float* __restrict__ Wl,
    const float* __restrict__ Wr, _Float16* __restrict__ outl,
    _Float16* __restrict__ outr, int nrows,
    const int* __restrict__ src, const int* __restrict__ dst,
    int* __restrict__ cursor, int* __restrict__ csr, int nedges)
{
    constexpr int KT = 64;                      // k-tile (LDS = 32 KB)
    __shared__ float4 sWl[KT * 16];             // [k][c4] : W[k][4c4..4c4+3]
    __shared__ float4 sWr[KT * 16];

    // ---- edge slice: coalesced loads issued up front ----
    int es[EPT], ed[EPT];
    const int e0 = blockIdx.x * (GTHREADS * EPT) + threadIdx.x;
    #pragma unroll
    for (int j = 0; j < EPT; ++j) {
        const int e = e0 + j * GTHREADS;
        const bool v = (e < nedges);
        es[j] = v ? src[e] : 0;
        ed[j] = v ? dst[e] : -1;                // -1 marks invalid
    }

    const int lane = threadIdx.x & 63;
    const int wid  = threadIdx.x >> 6;          // 0..7
    const int c4   = lane & 15;                 // col group
    const int rg   = lane >> 4;                 // 0..3 row-in-group
    const int wrow0 = blockIdx.x * (8 * 4 * R) + wid * (4 * R);

    int rr[R];
    #pragma unroll
    for (int r = 0; r < R; ++r) {
        const int row = wrow0 + r * 4 + rg;
        rr[r] = (row < nrows) ? row : (nrows - 1);   // clamp loads
    }

    float4 accl[R], accr[R];
    #pragma unroll
    for (int r = 0; r < R; ++r) {
        accl[r] = make_float4(0.f, 0.f, 0.f, 0.f);
        accr[r] = make_float4(0.f, 0.f, 0.f, 0.f);
    }

    auto do_tile = [&](int kt) {
        {   // stage W[kt .. kt+KT) (coalesced float4 copy)
            const float4* gWl = reinterpret_cast<const float4*>(Wl + kt * 64);
            const float4* gWr = reinterpret_cast<const float4*>(Wr + kt * 64);
            for (int i = threadIdx.x; i < KT * 16; i += GTHREADS) {
                sWl[i] = gWl[i];
                sWr[i] = gWr[i];
            }
        }
        __syncthreads();
        #pragma unroll 2
        for (int k4 = 0; k4 < KT / 4; ++k4) {
            float4 xv[R];
            #pragma unroll
            for (int r = 0; r < R; ++r)
                xv[r] = load4(in + (size_t)rr[r] * K + kt + k4 * 4);

            float4 wl[4], wr[4];
            #pragma unroll
            for (int j = 0; j < 4; ++j) {
                wl[j] = sWl[(k4 * 4 + j) * 16 + c4];
                wr[j] = sWr[(k4 * 4 + j) * 16 + c4];
            }
            #pragma unroll
            for (int r = 0; r < R; ++r) {
                const float x0 = xv[r].x, x1 = xv[r].y, x2 = xv[r].z, x3 = xv[r].w;
                accl[r].x = fmaf(x0, wl[0].x, accl[r].x);
                accl[r].y = fmaf(x0, wl[0].y, accl[r].y);
                accl[r].z = fmaf(x0, wl[0].z, accl[r].z);
                accl[r].w = fmaf(x0, wl[0].w, accl[r].w);
                accl[r].x = fmaf(x1, wl[1].x, accl[r].x);
                accl[r].y = fmaf(x1, wl[1].y, accl[r].y);
                accl[r].z = fmaf(x1, wl[1].z, accl[r].z);
                accl[r].w = fmaf(x1, wl[1].w, accl[r].w);
                accl[r].x = fmaf(x2, wl[2].x, accl[r].x);
                accl[r].y = fmaf(x2, wl[2].y, accl[r].y);
                accl[r].z = fmaf(x2, wl[2].z, accl[r].z);
                accl[r].w = fmaf(x2, wl[2].w, accl[r].w);
                accl[r].x = fmaf(x3, wl[3].x, accl[r].x);
                accl[r].y = fmaf(x3, wl[3].y, accl[r].y);
                accl[r].z = fmaf(x3, wl[3].z, accl[r].z);
                accl[r].w = fmaf(x3, wl[3].w, accl[r].w);

                accr[r].x = fmaf(x0, wr[0].x, accr[r].x);
                accr[r].y = fmaf(x0, wr[0].y, accr[r].y);
                accr[r].z = fmaf(x0, wr[0].z, accr[r].z);
                accr[r].w = fmaf(x0, wr[0].w, accr[r].w);
                accr[r].x = fmaf(x1, wr[1].x, accr[r].x);
                accr[r].y = fmaf(x1, wr[1].y, accr[r].y);
                accr[r].z = fmaf(x1, wr[1].z, accr[r].z);
                accr[r].w = fmaf(x1, wr[1].w, accr[r].w);
                accr[r].x = fmaf(x2, wr[2].x, accr[r].x);
                accr[r].y = fmaf(x2, wr[2].y, accr[r].y);
                accr[r].z = fmaf(x2, wr[2].z, accr[r].z);
                accr[r].w = fmaf(x2, wr[2].w, accr[r].w);
                accr[r].x = fmaf(x3, wr[3].x, accr[r].x);
                accr[r].y = fmaf(x3, wr[3].y, accr[r].y);
                accr[r].z = fmaf(x3, wr[3].z, accr[r].z);
                accr[r].w = fmaf(x3, wr[3].w, accr[r].w);
            }
        }
        __syncthreads();
    };

    // k-tile 0
    do_tile(0);

    // fire the placement atomics: independent, latency hides under the
    // remaining k-tiles / epilogue.
    int pos[EPT];
    #pragma unroll
    for (int j = 0; j < EPT; ++j)
        pos[j] = (ed[j] >= 0) ? atomicAdd(&cursor[ed[j]], 1) : 0;

    // remaining k-tiles
    for (int kt = KT; kt < K; kt += KT) do_tile(kt);

    // GEMM epilogue
    #pragma unroll
    for (int r = 0; r < R; ++r) {
        const int row = wrow0 + r * 4 + rg;
        if (row < nrows) {
            store4h(outl + (size_t)row * 64 + c4 * 4, accl[r]);
            store4h(outr + (size_t)row * 64 + c4 * 4, accr[r]);
        }
    }

    // placement stores (depend on atomic returns)
    #pragma unroll
    for (int j = 0; j < EPT; ++j)
        if (ed[j] >= 0) csr[pos[j]] = es[j];
}

// ---------------------------------------------------------------------------
// CSR build: histogram of dst, exclusive scan.
// ---------------------------------------------------------------------------
__global__ __launch_bounds__(THREADS) void hist_kernel(
    const int* __restrict__ dst, int* __restrict__ deg, int nedges)
{
    const int e = blockIdx.x * THREADS + threadIdx.x;
    if (e < nedges) atomicAdd(&deg[dst[e]], 1);
}

__global__ __launch_bounds__(THREADS) void scan_reduce(
    const int* __restrict__ deg, int* __restrict__ bsum, int n)
{
    __shared__ int s[THREADS];
    const int i = blockIdx.x * THREADS + threadIdx.x;
    s[threadIdx.x] = (i < n) ? deg[i] : 0;
    __syncthreads();
    for (int off = THREADS / 2; off > 0; off >>= 1) {
        if (threadIdx.x < off) s[threadIdx.x] += s[threadIdx.x + off];
        __syncthreads();
    }
    if (threadIdx.x == 0) bsum[blockIdx.x] = s[0];
}

// single block; nb <= THREADS
__global__ __launch_bounds__(THREADS) void scan_top(int* __restrict__ bsum, int nb)
{
    __shared__ int s[THREADS];
    const int t = threadIdx.x;
    const int v = (t < nb) ? bsum[t] : 0;
    s[t] = v;
    __syncthreads();
    for (int off = 1; off < THREADS; off <<= 1) {
        const int a = (t >= off) ? s[t - off] : 0;
        __syncthreads();
        s[t] += a;
        __syncthreads();
    }
    if (t < nb) bsum[t] = s[t] - v;   // exclusive
}

__global__ __launch_bounds__(THREADS) void scan_apply(
    const int* __restrict__ deg, const int* __restrict__ bsum,
    int* __restrict__ offs, int* __restrict__ cursor, int n)
{
    __shared__ int s[THREADS];
    const int t = threadIdx.x;
    const int i = blockIdx.x * THREADS + t;
    const int v = (i < n) ? deg[i] : 0;
    s[t] = v;
    __syncthreads();
    for (int off = 1; off < THREADS; off <<= 1) {
        const int a = (t >= off) ? s[t - off] : 0;
        __syncthreads();
        s[t] += a;
        __syncthreads();
    }
    if (i < n) {
        const int ex = bsum[blockIdx.x] + s[t] - v;
        offs[i] = ex;
        cursor[i] = ex;
    }
}

// ---------------------------------------------------------------------------
// Fused mean-aggregate + combine (fp16 payload, fp32 accumulation):
//   out[node,lane] = [relu]( (sum_{s in csr[node]} y[s,lane]) / max(deg,1)
//                            + bias[lane] + right[node,lane] )
// One wave per node, lane = channel (128B coalesced row reads).
// ---------------------------------------------------------------------------
__global__ __launch_bounds__(THREADS) void aggregate_fused(
    const _Float16* __restrict__ y, const int* __restrict__ csr,
    const int* __restrict__ offs, const int* __restrict__ deg,
    const _Float16* __restrict__ right, const float* __restrict__ bias,
    _Float16* __restrict__ out, int n, int relu)
{
    int node = blockIdx.x * (THREADS / 64) + (threadIdx.x >> 6);
    if (node >= n) return;
    node = __builtin_amdgcn_readfirstlane(node);   // wave-uniform
    const int lane = threadIdx.x & 63;
    const int start = __builtin_amdgcn_readfirstlane(offs[node]);
    const int d     = __builtin_amdgcn_readfirstlane(deg[node]);

    float acc = 0.f;
    int i = 0;
    for (; i + 4 <= d; i += 4) {
        const int s0 = __builtin_amdgcn_readfirstlane(csr[start + i + 0]);
        const int s1 = __builtin_amdgcn_readfirstlane(csr[start + i + 1]);
        const int s2 = __builtin_amdgcn_readfirstlane(csr[start + i + 2]);
        const int s3 = __builtin_amdgcn_readfirstlane(csr[start + i + 3]);
        const float a0 = (float)y[(size_t)s0 * 64 + lane];
        const float a1 = (float)y[(size_t)s1 * 64 + lane];
        const float a2 = (float)y[(size_t)s2 * 64 + lane];
        const float a3 = (float)y[(size_t)s3 * 64 + lane];
        acc += a0 + a1 + a2 + a3;
    }
    for (; i < d; ++i) {
        const int s = __builtin_amdgcn_readfirstlane(csr[start + i]);
        acc += (float)y[(size_t)s * 64 + lane];
    }

    const float inv = 1.0f / (float)(d > 0 ? d : 1);
    float v = fmaf(acc, inv, bias[lane] + (float)right[(size_t)node * 64 + lane]);
    if (relu) v = fmaxf(v, 0.f);
    out[(size_t)node * 64 + lane] = (_Float16)v;
}

// ---------------------------------------------------------------------------
// out[e] = dot(z[src[e]], z[dst[e]]) over 64 ch (fp16 z, fp32 accum);
// 8 lanes/edge, 16B loads, shfl reduce over 8.
// ---------------------------------------------------------------------------
__global__ __launch_bounds__(THREADS) void score_kernel(
    const _Float16* __restrict__ z, const int* __restrict__ src,
    const int* __restrict__ dst, float* __restrict__ out, int nedges)
{
    const int gid = blockIdx.x * THREADS + threadIdx.x;
    const int e = gid >> 3;
    const int g = gid & 7;
    if (e >= nedges) return;
    const int s = src[e];
    const int d = dst[e];
    const half8_t a = *reinterpret_cast<const half8_t*>(z + (size_t)s * 64 + g * 8);
    const half8_t b = *reinterpret_cast<const half8_t*>(z + (size_t)d * 64 + g * 8);
    float p = 0.f;
    #pragma unroll
    for (int j = 0; j < 8; ++j)
        p = fmaf((float)a[j], (float)b[j], p);
    p += __shfl_down(p, 4, 8);
    p += __shfl_down(p, 2, 8);
    p += __shfl_down(p, 1, 8);
    if (g == 0) out[e] = p;
}

extern "C" void kernel_launch(void* const* d_in, const int* in_sizes, int n_in,
                              void* d_out, int out_size, void* d_ws, size_t ws_size,
                              hipStream_t stream)
{
    const float* x   = (const float*)d_in[0];   // [N, 128]
    const int*   ei  = (const int*)  d_in[1];   // [2, E]
    const float* W1l = (const float*)d_in[2];   // [128, 64]
    const float* b1  = (const float*)d_in[3];   // [64]
    const float* W1r = (const float*)d_in[4];   // [128, 64]
    const float* W2l = (const float*)d_in[5];   // [64, 64]
    const float* b2  = (const float*)d_in[6];   // [64]
    const float* W2r = (const float*)d_in[7];   // [64, 64]
    float* out = (float*)d_out;

    const int N = in_sizes[0] / 128;            // 50000
    const int E = in_sizes[1] / 2;              // 800000
    const int* src = ei;
    const int* dst = ei + E;

    const size_t N64 = (size_t)N * 64;
    _Float16* tmp = (_Float16*)d_ws;            // [N,64]  in @ Wl (messages)
    _Float16* h   = tmp + N64;                  // [N,64]  layer-1 output
    _Float16* z   = h + N64;                    // [N,64]  layer-2 output
    int* deg    = (int*)(z + N64);              // [N]
    int* offs   = deg + N;                      // [N]
    int* cursor = offs + N;                     // [N]
    int* csr    = cursor + N;                   // [E]
    int* bsum   = csr + E;                      // [ceil(N/256)]

    constexpr int R = 4;                        // row-iters per lane
    constexpr int EPT = 4;                      // edges per thread (placement)
    const int rows_per_block = 8 * 4 * R;       // 8 waves x 4 rows x R = 128
    const int nb          = (N + THREADS - 1) / THREADS;       // scan blocks
    const int edge_blocks = (E + THREADS - 1) / THREADS;
    const int gemm_blocks = (N + rows_per_block - 1) / rows_per_block;  // 391
    const int aggr_blocks = (N + 3) / 4;                       // 4 nodes/block
    const int scor_blocks = (E * 8 + THREADS - 1) / THREADS;
    // 391 blocks x 512 thr x 4 edges = 800,768 >= E  (placement coverage)

    // ---- CSR prefix (histogram + scan; shared by both layers) ----
    hipMemsetAsync(deg, 0, (size_t)N * sizeof(int), stream);
    hist_kernel<<<edge_blocks, THREADS, 0, stream>>>(dst, deg, E);
    scan_reduce<<<nb, THREADS, 0, stream>>>(deg, bsum, N);
    scan_top<<<1, THREADS, 0, stream>>>(bsum, nb);
    scan_apply<<<nb, THREADS, 0, stream>>>(deg, bsum, offs, cursor, N);

    // ---- layer 1 GEMM with placement interleaved into every wave ----
    gemm_place<float, 128, R, EPT><<<gemm_blocks, GTHREADS, 0, stream>>>(
        x, W1l, W1r, tmp, h, N, src, dst, cursor, csr, E);
    aggregate_fused<<<aggr_blocks, THREADS, 0, stream>>>(tmp, csr, offs, deg, h, b1, h, N, 1);

    // ---- layer 2 ----
    gemm_place<_Float16, 64, R, EPT><<<gemm_blocks, GTHREADS, 0, stream>>>(
        h, W2l, W2r, tmp, z, N, nullptr, nullptr, nullptr, nullptr, 0);
    aggregate_fused<<<aggr_blocks, THREADS, 0, stream>>>(tmp, csr, offs, deg, z, b2, z, N, 0);

    // ---- decode ----
    score_kernel<<<scor_blocks, THREADS, 0, stream>>>(z, src, dst, out, E);
}